// Round 1
// baseline (199.946 us; speedup 1.0000x reference)
//
#include <hip/hip_runtime.h>

// BatchDelayProcessor: out[b,t] = x[b,t]*(1-MIX) + delayed[b,t]*MIX
//   delayed[t<D] = 0 ; delayed[t] = x[t-D] + FB*delayed[t-D]
// => per (b, i) column, a 20-step serial scan over blocks of D samples.
// Memory-bound: 226 MB total traffic, roofline ~36 us @ 6.3 TB/s.

constexpr int   kB    = 64;
constexpr int   kT    = 441000;
constexpr int   kD    = 22050;          // delay in samples
constexpr int   kNBLK = kT / kD;        // 20 blocks
constexpr float kFB   = 0.3f;
constexpr float kMIX  = 0.5f;

// float2 granularity: D = 22050 is even (11025 float2 per block-slice) and
// every block base offset k*D is even -> 8B-aligned float2 loads everywhere.
// (float4 impossible: D % 4 == 2, odd blocks misalign.)
constexpr int kHALF = kD / 2;           // 11025 float2 columns per block
constexpr int kTOTAL = kB * kHALF;      // 705600 threads

__global__ __launch_bounds__(256)
void delay_scan_kernel(const float* __restrict__ x, float* __restrict__ out) {
    int tid = blockIdx.x * blockDim.x + threadIdx.x;
    if (tid >= kTOTAL) return;
    int b = tid / kHALF;                // one non-pow2 div per thread, once
    int i = tid - b * kHALF;

    const float2* __restrict__ xp =
        reinterpret_cast<const float2*>(x + (size_t)b * kT) + i;
    float2* __restrict__ op =
        reinterpret_cast<float2*>(out + (size_t)b * kT) + i;

    constexpr int kSTRIDE2 = kD / 2;    // float2 stride between blocks

    float2 carry; carry.x = 0.0f; carry.y = 0.0f;
    float2 xv = xp[0];                  // prefetch block 0

    #pragma unroll
    for (int k = 0; k < kNBLK; ++k) {
        float2 nxt;
        if (k + 1 < kNBLK)              // compile-time after unroll
            nxt = xp[(size_t)(k + 1) * kSTRIDE2];

        float2 o;
        o.x = xv.x * (1.0f - kMIX) + carry.x * kMIX;
        o.y = xv.y * (1.0f - kMIX) + carry.y * kMIX;
        op[(size_t)k * kSTRIDE2] = o;

        carry.x = xv.x + kFB * carry.x; // lag-D recurrence
        carry.y = xv.y + kFB * carry.y;

        xv = nxt;
    }
}

extern "C" void kernel_launch(void* const* d_in, const int* in_sizes, int n_in,
                              void* d_out, int out_size, void* d_ws, size_t ws_size,
                              hipStream_t stream) {
    const float* x = (const float*)d_in[0];
    float* out = (float*)d_out;

    constexpr int kBlock = 256;
    constexpr int kGrid  = (kTOTAL + kBlock - 1) / kBlock;  // 2757 blocks
    delay_scan_kernel<<<kGrid, kBlock, 0, stream>>>(x, out);
}

// Round 2
// 199.330 us; speedup vs baseline: 1.0031x; 1.0031x over previous
//
#include <hip/hip_runtime.h>

// BatchDelayProcessor: out[b,t] = x[b,t]*(1-MIX) + delayed[b,t]*MIX
//   delayed[t<D] = 0 ; delayed[t] = x[t-D] + FB*delayed[t-D]
// => per (b, i) column, a 20-step serial scan over blocks of D samples.
//
// R1 lesson: 1-deep prefetch => VGPR=16, 20 serial HBM latencies, 2.5 TB/s.
// R2: load ALL 20 blocks into registers first (independent addresses), then
// run the carry chain. 20-deep MLP -> one latency, BW-bound.

constexpr int   kB    = 64;
constexpr int   kT    = 441000;
constexpr int   kD    = 22050;          // delay in samples
constexpr int   kNBLK = kT / kD;        // 20 blocks
constexpr float kFB   = 0.3f;
constexpr float kMIX  = 0.5f;

// float2 granularity: D = 22050 is even (11025 float2 per block-slice) and
// every block base offset k*D is even -> 8B-aligned float2 loads everywhere.
// (float4 impossible: D % 4 == 2, odd blocks misalign.)
constexpr int kHALF  = kD / 2;          // 11025 float2 columns per block
constexpr int kTOTAL = kB * kHALF;      // 705600 threads

__global__ __launch_bounds__(256)
void delay_scan_kernel(const float* __restrict__ x, float* __restrict__ out) {
    int tid = blockIdx.x * blockDim.x + threadIdx.x;
    if (tid >= kTOTAL) return;
    int b = tid / kHALF;                // magic-mul div, once per thread
    int i = tid - b * kHALF;

    const float2* __restrict__ xp =
        reinterpret_cast<const float2*>(x + (size_t)b * kT) + i;
    float2* __restrict__ op =
        reinterpret_cast<float2*>(out + (size_t)b * kT) + i;

    constexpr int kSTRIDE2 = kD / 2;    // float2 stride between blocks

    // Phase 1: issue all 20 independent loads back-to-back (20-deep MLP).
    // Static indexing after full unroll -> pure registers (40 VGPRs).
    float2 xv[kNBLK];
    #pragma unroll
    for (int k = 0; k < kNBLK; ++k)
        xv[k] = xp[(size_t)k * kSTRIDE2];

    // Phase 2: serial lag-D recurrence entirely in registers + stores.
    float2 carry; carry.x = 0.0f; carry.y = 0.0f;
    #pragma unroll
    for (int k = 0; k < kNBLK; ++k) {
        float2 o;
        o.x = xv[k].x * (1.0f - kMIX) + carry.x * kMIX;
        o.y = xv[k].y * (1.0f - kMIX) + carry.y * kMIX;
        op[(size_t)k * kSTRIDE2] = o;

        carry.x = xv[k].x + kFB * carry.x;
        carry.y = xv[k].y + kFB * carry.y;
    }
}

extern "C" void kernel_launch(void* const* d_in, const int* in_sizes, int n_in,
                              void* d_out, int out_size, void* d_ws, size_t ws_size,
                              hipStream_t stream) {
    const float* x = (const float*)d_in[0];
    float* out = (float*)d_out;

    constexpr int kBlock = 256;
    constexpr int kGrid  = (kTOTAL + kBlock - 1) / kBlock;  // 2757 blocks
    delay_scan_kernel<<<kGrid, kBlock, 0, stream>>>(x, out);
}